// Round 3
// baseline (76.645 us; speedup 1.0000x reference)
//
#include <hip/hip_runtime.h>
#include <cmath>

typedef unsigned short u16;
typedef __bf16 bf16x8 __attribute__((ext_vector_type(8)));
typedef float f32x4 __attribute__((ext_vector_type(4)));
typedef unsigned short u16x4 __attribute__((ext_vector_type(4)));

#define BATCH 16384
#define NTREE 32
#define NINT 63
#define NLEAF 64
#define FDIM 256

__device__ __forceinline__ u16 f2bf(float f) {
    unsigned int x = __float_as_uint(f);
    x += 0x7fffu + ((x >> 16) & 1u);   // round-to-nearest-even
    return (u16)(x >> 16);
}

__global__ void convert_kernel(const float* __restrict__ x, const float* __restrict__ W,
                               u16* __restrict__ xb, u16* __restrict__ Wb) {
    int idx = blockIdx.x * blockDim.x + threadIdx.x;
    int stride = gridDim.x * blockDim.x;
    const int NXQ = BATCH * FDIM / 4;
    for (int i = idx; i < NXQ; i += stride) {
        float4 v = ((const float4*)x)[i];
        u16x4 o = { f2bf(v.x), f2bf(v.y), f2bf(v.z), f2bf(v.w) };
        ((u16x4*)xb)[i] = o;
    }
    // Wb layout: [tree][64 nodes (63 real + 1 zero pad)][256 features], bf16
    const int NWQ = NTREE * NLEAF * FDIM / 4;
    for (int i = idx; i < NWQ; i += stride) {
        int t = i / (NLEAF * FDIM / 4);
        int r = i % (NLEAF * FDIM / 4);
        int node = r / (FDIM / 4);
        int kq = r % (FDIM / 4);
        float4 v = make_float4(0.f, 0.f, 0.f, 0.f);
        if (node < NINT) v = ((const float4*)(W + ((size_t)t * NINT + node) * FDIM))[kq];
        u16x4 o = { f2bf(v.x), f2bf(v.y), f2bf(v.z), f2bf(v.w) };
        ((u16x4*)Wb)[i] = o;
    }
}

// Block: 256 threads = 4 independent waves, one tree per block (W-tile L1-shared).
// Wave wv: 64 batch rows (m0+wv*64 ..), all 64 node-cols of tree t.
// GEMM fragments load DIRECTLY global->VGPR (no LDS staging, no barriers).
// LDS only for per-wave prob exchange, in two 32-row halves ([32][65] f32 slice).
__global__ __launch_bounds__(256, 4) void softgbm_main(
    const u16* __restrict__ xb, const u16* __restrict__ Wb,
    const float* __restrict__ bg, const float* __restrict__ phig,
    float* __restrict__ partial) {
    __shared__ float plds[4][32 * 65];   // 33.3 KB

    const int tid = threadIdx.x;
    const int lane = tid & 63, wv = tid >> 6;
    const int t = blockIdx.y;
    const int m0 = blockIdx.x * 256 + wv * 64;
    const int frow = lane & 15, lg = lane >> 4;

    // fragment global bases: lane reads 16B at (row, k = ks*32 + lg*8)
    const u16* abase = xb + (size_t)(m0 + frow) * FDIM + lg * 8;
    const u16* bbase = Wb + (size_t)(t * NLEAF + frow) * FDIM + lg * 8;

    f32x4 acc[4][4] = {};
    #pragma unroll
    for (int ks = 0; ks < 8; ++ks) {
        bf16x8 af[4], bf_[4];
        #pragma unroll
        for (int ar = 0; ar < 4; ++ar)
            af[ar] = *(const bf16x8*)(abase + ar * 16 * FDIM + ks * 32);
        #pragma unroll
        for (int bc = 0; bc < 4; ++bc)
            bf_[bc] = *(const bf16x8*)(bbase + bc * 16 * FDIM + ks * 32);
        #pragma unroll
        for (int ar = 0; ar < 4; ++ar)
            #pragma unroll
            for (int bc = 0; bc < 4; ++bc)
                acc[ar][bc] = __builtin_amdgcn_mfma_f32_16x16x32_bf16(af[ar], bf_[bc], acc[ar][bc], 0, 0, 0);
    }

    float bv[4];
    #pragma unroll
    for (int bc = 0; bc < 4; ++bc) {
        int col = bc * 16 + frow;
        bv[bc] = (col < NINT) ? bg[t * NINT + col] : 0.f;
    }

    float* pl = plds[wv];
    const int r = lane & 31, hl = lane >> 5;
    const float* pr = pl + r * 65;
    const float* pf = phig + (size_t)t * NLEAF + hl * 32;
    float out_s[2];

    #pragma unroll
    for (int h = 0; h < 2; ++h) {
        // ---- sigmoid + scatter 32 probs (rows h*32..h*32+31 -> slice rows 0..31)
        #pragma unroll
        for (int a2 = 0; a2 < 2; ++a2) {
            int ar = h * 2 + a2;
            #pragma unroll
            for (int bc = 0; bc < 4; ++bc)
                #pragma unroll
                for (int j = 0; j < 4; ++j) {
                    int row = a2 * 16 + lg * 4 + j;   // C/D: row=(lane>>4)*4+reg
                    int col = bc * 16 + frow;         //      col=lane&15
                    float z = acc[ar][bc][j] + bv[bc];
                    pl[row * 65 + col] = __builtin_amdgcn_rcpf(1.f + __expf(-z));
                }
        }
        // DS ops within a wave are processed in order; fence against any reorder.
        asm volatile("s_waitcnt lgkmcnt(0)" ::: "memory");
        __builtin_amdgcn_sched_barrier(0);

        // ---- tree eval: lane = (row r, leaf-half hl), 16 depth-5 nodes each
        float p0 = pr[0];
        float mu[16];
        mu[0] = hl ? p0 : 1.f - p0;               // depth-1 node of our subtree
        #pragma unroll
        for (int d = 1; d < 5; ++d) {             // read nodes at depth d
            int n = 1 << (d - 1);                 // current mu count
            int off = (1 << d) - 1 + hl * n;      // our subtree's nodes at depth d
            #pragma unroll
            for (int i = n - 1; i >= 0; --i) {
                float p = pr[off + i];
                float m = mu[i];
                float tt = m * p;
                mu[2 * i + 1] = tt;
                mu[2 * i] = m - tt;
            }
        }
        float s = 0.f;
        #pragma unroll
        for (int i = 0; i < 16; ++i) {            // depth-5 node i -> leaf pair
            float p = pr[31 + hl * 16 + i];
            float a = pf[2 * i], b2 = pf[2 * i + 1];
            s += mu[i] * (a + p * (b2 - a));
        }
        s += __shfl_xor(s, 32);                   // combine the two leaf-halves
        out_s[h] = s;

        if (h == 0) {   // slice reused by half 1: ensure reads drained (in-order DS + fence)
            asm volatile("s_waitcnt lgkmcnt(0)" ::: "memory");
            __builtin_amdgcn_sched_barrier(0);
        }
    }

    if (lane < 32) {
        partial[(size_t)t * BATCH + m0 + r]      = out_s[0];
        partial[(size_t)t * BATCH + m0 + 32 + r] = out_s[1];
    }
}

__global__ void reduce_kernel(const float* __restrict__ partial, float* __restrict__ out) {
    int i = blockIdx.x * 256 + threadIdx.x;
    float s = 0.f;
    #pragma unroll
    for (int t = 0; t < NTREE; ++t) s += partial[(size_t)t * BATCH + i];
    out[i] = 0.1f * s;
}

extern "C" void kernel_launch(void* const* d_in, const int* in_sizes, int n_in,
                              void* d_out, int out_size, void* d_ws, size_t ws_size,
                              hipStream_t stream) {
    const float* x   = (const float*)d_in[0];
    const float* W   = (const float*)d_in[1];
    const float* b   = (const float*)d_in[2];
    const float* phi = (const float*)d_in[3];
    float* out = (float*)d_out;

    u16* xb = (u16*)d_ws;                                  // 16384*256 bf16 = 8 MB
    u16* Wb = xb + (size_t)BATCH * FDIM;                   // 32*64*256 bf16 = 1 MB
    float* partial = (float*)(Wb + (size_t)NTREE * NLEAF * FDIM);  // 32*16384 f32 = 2 MB

    convert_kernel<<<2048, 256, 0, stream>>>(x, W, xb, Wb);
    softgbm_main<<<dim3(BATCH / 256, NTREE), 256, 0, stream>>>(xb, Wb, b, phi, partial);
    reduce_kernel<<<BATCH / 256, 256, 0, stream>>>(partial, out);
}

// Round 4
// 45.237 us; speedup vs baseline: 1.6943x; 1.6943x over previous
//
#include <hip/hip_runtime.h>
#include <cmath>

typedef unsigned short u16;
typedef __bf16 bf16x8 __attribute__((ext_vector_type(8)));
typedef float f32x4 __attribute__((ext_vector_type(4)));
typedef unsigned short u16x4 __attribute__((ext_vector_type(4)));

#define BATCH 16384
#define NTREE 32
#define NINT 63
#define NLEAF 64
#define FDIM 256
#define MT 128     // batch rows per block
#define BK 64      // K per staging step
#define KSTEPS 4   // 256/64

typedef __attribute__((address_space(3))) void lvoid;
typedef __attribute__((address_space(1))) const void gvoid;
__device__ __forceinline__ void gload16(const void* g, void* l) {
    // DMA 16B/lane global->LDS; LDS dest = uniform base + lane*16 (HW rule)
    __builtin_amdgcn_global_load_lds((gvoid*)g, (lvoid*)l, 16, 0, 0);
}

__device__ __forceinline__ u16 f2bf(float f) {
    unsigned int x = __float_as_uint(f);
    x += 0x7fffu + ((x >> 16) & 1u);   // round-to-nearest-even
    return (u16)(x >> 16);
}

__global__ void convert_kernel(const float* __restrict__ x, const float* __restrict__ W,
                               u16* __restrict__ xb, u16* __restrict__ Wb) {
    int idx = blockIdx.x * blockDim.x + threadIdx.x;
    int stride = gridDim.x * blockDim.x;
    const int NXQ = BATCH * FDIM / 4;
    for (int i = idx; i < NXQ; i += stride) {
        float4 v = ((const float4*)x)[i];
        u16x4 o = { f2bf(v.x), f2bf(v.y), f2bf(v.z), f2bf(v.w) };
        ((u16x4*)xb)[i] = o;
    }
    // Wb layout: [tree][64 nodes (63 real + 1 zero pad)][256 features], bf16
    const int NWQ = NTREE * NLEAF * FDIM / 4;
    for (int i = idx; i < NWQ; i += stride) {
        int t = i / (NLEAF * FDIM / 4);
        int r = i % (NLEAF * FDIM / 4);
        int node = r / (FDIM / 4);
        int kq = r % (FDIM / 4);
        float4 v = make_float4(0.f, 0.f, 0.f, 0.f);
        if (node < NINT) v = ((const float4*)(W + ((size_t)t * NINT + node) * FDIM))[kq];
        u16x4 o = { f2bf(v.x), f2bf(v.y), f2bf(v.z), f2bf(v.w) };
        ((u16x4*)Wb)[i] = o;
    }
}

// Block: 256 thr = 4 waves, 128 batch rows x 1 tree. Wave (wr,wc): rows wr*64..+63,
// cols wc*32..+31 (acc 4x2 frags = 32 VGPR). A(128xBK)+B(64xBK) double-buffered in LDS,
// filled by global_load_lds DMA (zero VGPR cost). XOR swizzle cc^(row&7) applied on the
// GLOBAL source and the ds_read side (rule 21: linear DMA dest + pre-swizzled source).
__global__ __launch_bounds__(256, 3) void softgbm_main(
    const u16* __restrict__ xb, const u16* __restrict__ Wb,
    const float* __restrict__ bg, const float* __restrict__ phig,
    float* __restrict__ partial) {
    union ShMem {
        struct { u16 A[2][MT * BK]; u16 B[2][NLEAF * BK]; } s;  // 32KB + 16KB
        struct { float p[MT * 65]; float phi[NLEAF]; } e;       // 33.5KB
    };
    __shared__ ShMem sh;

    const int tid = threadIdx.x;
    const int lane = tid & 63, wv = tid >> 6;
    const int t = blockIdx.y;
    const int m0 = blockIdx.x * MT;

    // ---- staging pointers (pre-swizzled global source). 16B chunk = 8 u16.
    // A: 1024 chunks/buffer -> 4 issues/wave; B: 512 -> 2 issues/wave.
    const u16* agp[4]; const u16* bgp[2];
    #pragma unroll
    for (int j = 0; j < 4; ++j) {
        int cl = wv * 256 + j * 64 + lane;          // linear LDS chunk id
        int row = cl >> 3, pcc = cl & 7;
        int cc = pcc ^ (row & 7);                   // global chunk (involution)
        agp[j] = xb + (size_t)(m0 + row) * FDIM + cc * 8;
    }
    #pragma unroll
    for (int j = 0; j < 2; ++j) {
        int cl = wv * 128 + j * 64 + lane;
        int row = cl >> 3, pcc = cl & 7;
        int cc = pcc ^ (row & 7);
        bgp[j] = Wb + (size_t)(t * NLEAF + row) * FDIM + cc * 8;
    }

    // ---- frag read LDS byte-offsets (same XOR on read side)
    const int wr = wv >> 1, wc = wv & 1;
    const int frow = lane & 15, lg = lane >> 4;
    int aoffs[4][2], boffs[2][2];
    #pragma unroll
    for (int ar = 0; ar < 4; ++ar) {
        int r = wr * 64 + ar * 16 + frow;
        #pragma unroll
        for (int ks = 0; ks < 2; ++ks) {
            int cc = ks * 4 + lg;
            aoffs[ar][ks] = r * 128 + ((cc ^ (r & 7)) * 16);
        }
    }
    #pragma unroll
    for (int bc = 0; bc < 2; ++bc) {
        int n = wc * 32 + bc * 16 + frow;
        #pragma unroll
        for (int ks = 0; ks < 2; ++ks) {
            int cc = ks * 4 + lg;
            boffs[bc][ks] = n * 128 + ((cc ^ (n & 7)) * 16);
        }
    }

    float bv[2];
    #pragma unroll
    for (int bc = 0; bc < 2; ++bc) {
        int col = wc * 32 + bc * 16 + frow;
        bv[bc] = (col < NINT) ? bg[t * NINT + col] : 0.f;
    }

    // ---- prologue: stage step 0 into buf 0
    #pragma unroll
    for (int j = 0; j < 4; ++j)
        gload16(agp[j], &sh.s.A[0][(wv * 256 + j * 64) * 8]);
    #pragma unroll
    for (int j = 0; j < 2; ++j)
        gload16(bgp[j], &sh.s.B[0][(wv * 128 + j * 64) * 8]);
    __syncthreads();

    f32x4 acc[4][2] = {};
    #pragma unroll
    for (int st = 0; st < KSTEPS; ++st) {
        int cur = st & 1;
        if (st < KSTEPS - 1) {     // DMA next K-step into the other buffer
            int nxt = cur ^ 1;
            #pragma unroll
            for (int j = 0; j < 4; ++j)
                gload16(agp[j] + (st + 1) * BK, &sh.s.A[nxt][(wv * 256 + j * 64) * 8]);
            #pragma unroll
            for (int j = 0; j < 2; ++j)
                gload16(bgp[j] + (st + 1) * BK, &sh.s.B[nxt][(wv * 128 + j * 64) * 8]);
        }
        const char* Ab = (const char*)sh.s.A[cur];
        const char* Bb = (const char*)sh.s.B[cur];
        #pragma unroll
        for (int ks = 0; ks < 2; ++ks) {
            bf16x8 af[4], bf_[2];
            #pragma unroll
            for (int ar = 0; ar < 4; ++ar) af[ar] = *(const bf16x8*)(Ab + aoffs[ar][ks]);
            #pragma unroll
            for (int bc = 0; bc < 2; ++bc) bf_[bc] = *(const bf16x8*)(Bb + boffs[bc][ks]);
            #pragma unroll
            for (int ar = 0; ar < 4; ++ar)
                #pragma unroll
                for (int bc = 0; bc < 2; ++bc)
                    acc[ar][bc] = __builtin_amdgcn_mfma_f32_16x16x32_bf16(af[ar], bf_[bc], acc[ar][bc], 0, 0, 0);
        }
        __syncthreads();   // drains DMA (vmcnt) + frag reads; buffers safe to swap
    }

    // ---- epilogue: sigmoid + scatter probs (p aliases staging buffers; barrier above)
    if (tid < NLEAF) sh.e.phi[tid] = phig[(size_t)t * NLEAF + tid];
    #pragma unroll
    for (int ar = 0; ar < 4; ++ar)
        #pragma unroll
        for (int bc = 0; bc < 2; ++bc)
            #pragma unroll
            for (int j = 0; j < 4; ++j) {
                int row = wr * 64 + ar * 16 + lg * 4 + j;   // C/D: row=(lane>>4)*4+reg
                int col = wc * 32 + bc * 16 + frow;         //      col=lane&15
                float z = acc[ar][bc][j] + bv[bc];
                sh.e.p[row * 65 + col] = __builtin_amdgcn_rcpf(1.f + __expf(-z));
            }
    __syncthreads();

    // ---- tree eval: thread = (row, leaf-half). 2 thr/row x 128 rows.
    {
        const int row = tid >> 1, hl = tid & 1;
        const float* pr = sh.e.p + row * 65;
        const float* pf = sh.e.phi + hl * 32;
        float p0 = pr[0];
        float mu[16];
        mu[0] = hl ? p0 : 1.f - p0;               // depth-1 node of our subtree
        #pragma unroll
        for (int d = 1; d < 5; ++d) {
            int n = 1 << (d - 1);
            int off = (1 << d) - 1 + hl * n;
            #pragma unroll
            for (int i = n - 1; i >= 0; --i) {
                float p = pr[off + i];
                float m = mu[i];
                float tt = m * p;
                mu[2 * i + 1] = tt;
                mu[2 * i] = m - tt;
            }
        }
        float s = 0.f;
        #pragma unroll
        for (int i = 0; i < 16; ++i) {            // depth-5 node -> leaf pair interp
            float p = pr[31 + hl * 16 + i];
            float a = pf[2 * i], b2 = pf[2 * i + 1];
            s += mu[i] * (a + p * (b2 - a));
        }
        s += __shfl_xor(s, 1);
        if (!hl) partial[(size_t)t * BATCH + m0 + row] = s;
    }
}

__global__ void reduce_kernel(const float* __restrict__ partial, float* __restrict__ out) {
    int i = blockIdx.x * 256 + threadIdx.x;
    float s = 0.f;
    #pragma unroll
    for (int t = 0; t < NTREE; ++t) s += partial[(size_t)t * BATCH + i];
    out[i] = 0.1f * s;
}

extern "C" void kernel_launch(void* const* d_in, const int* in_sizes, int n_in,
                              void* d_out, int out_size, void* d_ws, size_t ws_size,
                              hipStream_t stream) {
    const float* x   = (const float*)d_in[0];
    const float* W   = (const float*)d_in[1];
    const float* b   = (const float*)d_in[2];
    const float* phi = (const float*)d_in[3];
    float* out = (float*)d_out;

    u16* xb = (u16*)d_ws;                                  // 16384*256 bf16 = 8 MB
    u16* Wb = xb + (size_t)BATCH * FDIM;                   // 32*64*256 bf16 = 1 MB
    float* partial = (float*)(Wb + (size_t)NTREE * NLEAF * FDIM);  // 32*16384 f32 = 2 MB

    convert_kernel<<<2048, 256, 0, stream>>>(x, W, xb, Wb);
    softgbm_main<<<dim3(BATCH / MT, NTREE), 256, 0, stream>>>(xb, Wb, b, phi, partial);
    reduce_kernel<<<BATCH / 256, 256, 0, stream>>>(partial, out);
}

// Round 5
// 43.065 us; speedup vs baseline: 1.7798x; 1.0504x over previous
//
#include <hip/hip_runtime.h>
#include <cmath>

typedef unsigned short u16;
typedef __bf16 bf16x8 __attribute__((ext_vector_type(8)));
typedef float f32x4 __attribute__((ext_vector_type(4)));
typedef unsigned short u16x4 __attribute__((ext_vector_type(4)));

#define BATCH 16384
#define NTREE 32
#define NINT 63
#define NLEAF 64
#define FDIM 256
#define MT 128     // batch rows per block
#define TPB 2      // trees per block (128 node-cols)
#define BK 64      // K per staging step
#define KSTEPS 4   // 256/64

typedef __attribute__((address_space(3))) void lvoid;
typedef __attribute__((address_space(1))) const void gvoid;
__device__ __forceinline__ void gload16(const void* g, void* l) {
    // DMA 16B/lane global->LDS; LDS dest = uniform base + lane*16 (HW rule)
    __builtin_amdgcn_global_load_lds((gvoid*)g, (lvoid*)l, 16, 0, 0);
}

__device__ __forceinline__ u16 f2bf(float f) {
    unsigned int x = __float_as_uint(f);
    x += 0x7fffu + ((x >> 16) & 1u);   // round-to-nearest-even
    return (u16)(x >> 16);
}

__global__ void convert_kernel(const float* __restrict__ x, const float* __restrict__ W,
                               u16* __restrict__ xb, u16* __restrict__ Wb) {
    int idx = blockIdx.x * blockDim.x + threadIdx.x;
    int stride = gridDim.x * blockDim.x;
    const int NXQ = BATCH * FDIM / 4;
    for (int i = idx; i < NXQ; i += stride) {
        float4 v = ((const float4*)x)[i];
        u16x4 o = { f2bf(v.x), f2bf(v.y), f2bf(v.z), f2bf(v.w) };
        ((u16x4*)xb)[i] = o;
    }
    // Wb layout: [tree][64 nodes (63 real + 1 zero pad)][256 features], bf16
    const int NWQ = NTREE * NLEAF * FDIM / 4;
    for (int i = idx; i < NWQ; i += stride) {
        int t = i / (NLEAF * FDIM / 4);
        int r = i % (NLEAF * FDIM / 4);
        int node = r / (FDIM / 4);
        int kq = r % (FDIM / 4);
        float4 v = make_float4(0.f, 0.f, 0.f, 0.f);
        if (node < NINT) v = ((const float4*)(W + ((size_t)t * NINT + node) * FDIM))[kq];
        u16x4 o = { f2bf(v.x), f2bf(v.y), f2bf(v.z), f2bf(v.w) };
        ((u16x4*)Wb)[i] = o;
    }
}

// Block: 256 thr = 4 waves (2x2), 128 batch rows x 2 trees (128 node-cols).
// Wave (wr,wc): rows wr*64..+63, tree wc's 64 cols. acc 4x4 frags (64 VGPR).
// A(128xBK)+B(128xBK) double-buffered in LDS via global_load_lds DMA (zero VGPR).
// XOR swizzle cc^(row&7) on the GLOBAL source and the ds_read side (rule 21).
__global__ __launch_bounds__(256) void softgbm_main(
    const u16* __restrict__ xb, const u16* __restrict__ Wb,
    const float* __restrict__ bg, const float* __restrict__ phig,
    float* __restrict__ partial) {
    union ShMem {
        struct { u16 A[2][MT * BK]; u16 B[2][TPB * NLEAF * BK]; } s;  // 32KB + 32KB
        struct { float p[TPB][MT][65]; float phi[TPB][NLEAF]; } e;    // 66.5KB + 0.5KB
    };
    __shared__ ShMem sh;

    const int tid = threadIdx.x;
    const int lane = tid & 63, wv = tid >> 6;
    const int t0 = blockIdx.y * TPB;
    const int m0 = blockIdx.x * MT;
    const int bw0 = blockIdx.y * TPB * NLEAF;   // first Wb row of this block's B tile

    // ---- staging pointers (pre-swizzled global source). 16B chunk = 8 u16.
    // A: 1024 chunks/buffer, B: 1024 -> 4+4 issues/wave.
    const u16* agp[4]; const u16* bgp[4];
    #pragma unroll
    for (int j = 0; j < 4; ++j) {
        int cl = wv * 256 + j * 64 + lane;          // linear LDS chunk id
        int row = cl >> 3, pcc = cl & 7;
        int cc = pcc ^ (row & 7);                   // global chunk (involution)
        agp[j] = xb + (size_t)(m0 + row) * FDIM + cc * 8;
        bgp[j] = Wb + (size_t)(bw0 + row) * FDIM + cc * 8;
    }

    // ---- frag read LDS byte-offsets (same XOR on read side)
    const int wr = wv >> 1, wc = wv & 1;
    const int frow = lane & 15, lg = lane >> 4;
    int aoffs[4][2], boffs[4][2];
    #pragma unroll
    for (int ar = 0; ar < 4; ++ar) {
        int r = wr * 64 + ar * 16 + frow;
        #pragma unroll
        for (int ks = 0; ks < 2; ++ks) {
            int cc = ks * 4 + lg;
            aoffs[ar][ks] = r * 128 + ((cc ^ (r & 7)) * 16);
        }
    }
    #pragma unroll
    for (int bc = 0; bc < 4; ++bc) {
        int n = wc * 64 + bc * 16 + frow;           // Wb-row within tile (tree wc, node)
        #pragma unroll
        for (int ks = 0; ks < 2; ++ks) {
            int cc = ks * 4 + lg;
            boffs[bc][ks] = n * 128 + ((cc ^ (n & 7)) * 16);
        }
    }

    float bv[4];
    #pragma unroll
    for (int bc = 0; bc < 4; ++bc) {
        int col = bc * 16 + frow;
        bv[bc] = (col < NINT) ? bg[(t0 + wc) * NINT + col] : 0.f;
    }
    // phi region (bytes 66560+) doesn't alias the 64KB staging region -> safe early
    if (tid < TPB * NLEAF)
        sh.e.phi[tid >> 6][tid & 63] = phig[(size_t)(t0 + (tid >> 6)) * NLEAF + (tid & 63)];

    // ---- prologue: stage step 0 into buf 0
    #pragma unroll
    for (int j = 0; j < 4; ++j) {
        gload16(agp[j], &sh.s.A[0][(wv * 256 + j * 64) * 8]);
        gload16(bgp[j], &sh.s.B[0][(wv * 256 + j * 64) * 8]);
    }
    __syncthreads();

    f32x4 acc[4][4] = {};
    #pragma unroll
    for (int st = 0; st < KSTEPS; ++st) {
        int cur = st & 1;
        if (st < KSTEPS - 1) {     // DMA next K-step into the other buffer
            int nxt = cur ^ 1;
            #pragma unroll
            for (int j = 0; j < 4; ++j) {
                gload16(agp[j] + (st + 1) * BK, &sh.s.A[nxt][(wv * 256 + j * 64) * 8]);
                gload16(bgp[j] + (st + 1) * BK, &sh.s.B[nxt][(wv * 256 + j * 64) * 8]);
            }
        }
        const char* Ab = (const char*)sh.s.A[cur];
        const char* Bb = (const char*)sh.s.B[cur];
        #pragma unroll
        for (int ks = 0; ks < 2; ++ks) {
            bf16x8 af[4], bf_[4];
            #pragma unroll
            for (int ar = 0; ar < 4; ++ar) af[ar] = *(const bf16x8*)(Ab + aoffs[ar][ks]);
            #pragma unroll
            for (int bc = 0; bc < 4; ++bc) bf_[bc] = *(const bf16x8*)(Bb + boffs[bc][ks]);
            #pragma unroll
            for (int ar = 0; ar < 4; ++ar)
                #pragma unroll
                for (int bc = 0; bc < 4; ++bc)
                    acc[ar][bc] = __builtin_amdgcn_mfma_f32_16x16x32_bf16(af[ar], bf_[bc], acc[ar][bc], 0, 0, 0);
        }
        __syncthreads();   // drains DMA (vmcnt) + frag reads; buffers safe to swap
    }

    // ---- epilogue: sigmoid + scatter probs (p aliases staging; barrier above)
    #pragma unroll
    for (int ar = 0; ar < 4; ++ar)
        #pragma unroll
        for (int bc = 0; bc < 4; ++bc)
            #pragma unroll
            for (int j = 0; j < 4; ++j) {
                int row = wr * 64 + ar * 16 + lg * 4 + j;   // C/D: row=(lane>>4)*4+reg
                int col = bc * 16 + frow;                   //      col=lane&15
                float z = acc[ar][bc][j] + bv[bc];
                sh.e.p[wc][row][col] = __builtin_amdgcn_rcpf(1.f + __expf(-z));
            }
    __syncthreads();

    // ---- tree eval: thread = (tree, row). Full 63-node expansion per thread.
    {
        const int th = tid >> 7, row = tid & (MT - 1);
        const float* pr = &sh.e.p[th][row][0];
        const float* pf = sh.e.phi[th];
        float mu[32];
        float p0 = pr[0];
        mu[0] = 1.f - p0; mu[1] = p0;
        #pragma unroll
        for (int d = 1; d < 5; ++d) {
            int n = 1 << d;
            int off = n - 1;
            #pragma unroll
            for (int i = n - 1; i >= 0; --i) {
                float p = pr[off + i];
                float m = mu[i];
                float tt = m * p;
                mu[2 * i + 1] = tt;
                mu[2 * i] = m - tt;
            }
        }
        float s = 0.f;
        #pragma unroll
        for (int i = 0; i < 32; ++i) {            // depth-5 node -> leaf pair interp
            float p = pr[31 + i];
            float a = pf[2 * i], b2 = pf[2 * i + 1];
            s += mu[i] * (a + p * (b2 - a));
        }
        partial[(size_t)(t0 + th) * BATCH + m0 + row] = s;
    }
}

__global__ void reduce_kernel(const float* __restrict__ partial, float* __restrict__ out) {
    int i = blockIdx.x * 256 + threadIdx.x;
    float s = 0.f;
    #pragma unroll
    for (int t = 0; t < NTREE; ++t) s += partial[(size_t)t * BATCH + i];
    out[i] = 0.1f * s;
}

extern "C" void kernel_launch(void* const* d_in, const int* in_sizes, int n_in,
                              void* d_out, int out_size, void* d_ws, size_t ws_size,
                              hipStream_t stream) {
    const float* x   = (const float*)d_in[0];
    const float* W   = (const float*)d_in[1];
    const float* b   = (const float*)d_in[2];
    const float* phi = (const float*)d_in[3];
    float* out = (float*)d_out;

    u16* xb = (u16*)d_ws;                                  // 16384*256 bf16 = 8 MB
    u16* Wb = xb + (size_t)BATCH * FDIM;                   // 32*64*256 bf16 = 1 MB
    float* partial = (float*)(Wb + (size_t)NTREE * NLEAF * FDIM);  // 32*16384 f32 = 2 MB

    convert_kernel<<<2048, 256, 0, stream>>>(x, W, xb, Wb);
    softgbm_main<<<dim3(BATCH / MT, NTREE / TPB), 256, 0, stream>>>(xb, Wb, b, phi, partial);
    reduce_kernel<<<BATCH / 256, 256, 0, stream>>>(partial, out);
}

// Round 6
// 37.602 us; speedup vs baseline: 2.0383x; 1.1453x over previous
//
#include <hip/hip_runtime.h>
#include <cmath>

typedef unsigned short u16;
typedef __bf16 bf16x8 __attribute__((ext_vector_type(8)));
typedef float f32x4 __attribute__((ext_vector_type(4)));
typedef unsigned short u16x4 __attribute__((ext_vector_type(4)));

#define BATCH 16384
#define NTREE 32
#define NINT 63
#define NLEAF 64
#define FDIM 256
#define MT 128     // batch rows per block
#define TPB 2      // trees per block
#define BK 64      // K per staging step
#define KSTEPS 4   // 256/64

typedef __attribute__((address_space(3))) void lvoid;
typedef __attribute__((address_space(1))) const void gvoid;
__device__ __forceinline__ void gload16(const void* g, void* l) {
    // DMA 16B/lane global->LDS; LDS dest = wave-uniform base + lane*16 (HW rule)
    __builtin_amdgcn_global_load_lds((gvoid*)g, (lvoid*)l, 16, 0, 0);
}

__device__ __forceinline__ u16 f2bf(float f) {
    unsigned int x = __float_as_uint(f);
    x += 0x7fffu + ((x >> 16) & 1u);   // round-to-nearest-even
    return (u16)(x >> 16);
}

// D-row slot s (0..63) -> heap node id. Lane-group lg = (s>>2)&3 owns depth-2
// subtree lg; local v = (s>>4)*4 + (s&3): v=0 extra (root dup / depth-1 node),
// v=1 d2 node, v=2,3 d3, v=4..7 d4, v=8..15 d5.
__device__ __forceinline__ int slot2node(int slot) {
    int lg = (slot >> 2) & 3;
    int v = ((slot >> 4) << 2) | (slot & 3);
    if (v == 0)  return (lg & 1) ? (1 + (lg >> 1)) : 0;
    if (v == 1)  return 3 + lg;
    if (v < 4)   return 7 + 2 * lg + (v - 2);
    if (v < 8)   return 15 + 4 * lg + (v - 4);
    return 31 + 8 * lg + (v - 8);
}

__global__ void convert_kernel(const float* __restrict__ x, const float* __restrict__ W,
                               const float* __restrict__ b,
                               u16* __restrict__ xb, u16* __restrict__ Wb,
                               float* __restrict__ bperm) {
    int idx = blockIdx.x * blockDim.x + threadIdx.x;
    int stride = gridDim.x * blockDim.x;
    const int NXQ = BATCH * FDIM / 4;
    for (int i = idx; i < NXQ; i += stride) {
        float4 v = ((const float4*)x)[i];
        u16x4 o = { f2bf(v.x), f2bf(v.y), f2bf(v.z), f2bf(v.w) };
        ((u16x4*)xb)[i] = o;
    }
    // Wb: [tree][64 slots (permuted nodes, root duplicated)][256 features]
    const int NWQ = NTREE * NLEAF * FDIM / 4;
    for (int i = idx; i < NWQ; i += stride) {
        int t = i / (NLEAF * FDIM / 4);
        int r = i % (NLEAF * FDIM / 4);
        int slot = r / (FDIM / 4);
        int kq = r % (FDIM / 4);
        int node = slot2node(slot);
        float4 v = ((const float4*)(W + ((size_t)t * NINT + node) * FDIM))[kq];
        u16x4 o = { f2bf(v.x), f2bf(v.y), f2bf(v.z), f2bf(v.w) };
        ((u16x4*)Wb)[i] = o;
    }
    // permuted bias table (f32, exact)
    if (idx < NTREE * NLEAF)
        bperm[idx] = b[(idx >> 6) * NINT + slot2node(idx & 63)];
}

// Block: 256 thr = 4 waves, 128 batch rows x 2 trees. Wave (th=wv&1, rh=wv>>1):
// tree th, batch rows rh*64..+63. SWAPPED GEMM: A = W slots (D-rows = nodes),
// B = x rows (D-cols = batch rows). acc 4x4 frags (64 VGPR).
// A(128xBK)+B(128xBK) single-buffered 32KB LDS via global_load_lds DMA;
// XOR swizzle cc^(row&7) on GLOBAL source + ds_read side (rule 21, R5-proven).
// Epilogue is 100% in-register: no LDS, no barriers.
__global__ __launch_bounds__(256, 3) void softgbm_main(
    const u16* __restrict__ xb, const u16* __restrict__ Wb,
    const float* __restrict__ bperm, const float* __restrict__ phig,
    float* __restrict__ partial) {
    __shared__ u16 Ash[MT * BK];   // 16KB: 2 trees x 64 slots
    __shared__ u16 Bsh[MT * BK];   // 16KB: 128 x-rows

    const int tid = threadIdx.x;
    const int lane = tid & 63, wv = tid >> 6;
    const int t0 = blockIdx.y * TPB;
    const int m0 = blockIdx.x * MT;
    const int th = wv & 1, rh = wv >> 1;
    const int frow = lane & 15, lg = lane >> 4, f7 = frow & 7;

    // ---- DMA source (pre-swizzled global; j-invariant: +j*8 rows)
    const int row0 = wv * 32 + (lane >> 3);
    const int cc = (lane & 7) ^ ((lane >> 3) & 7);
    const u16* ag = Wb + (size_t)(t0 * NLEAF + row0) * FDIM + cc * 8;
    const u16* bg2 = xb + (size_t)(m0 + row0) * FDIM + cc * 8;

    // ---- frag read offsets: byte = row*128 + ((ks*4+lg)^f7)*16 ; row&7 == f7
    const int abase = (th * 64 + frow) * 128;
    const int bbase = (rh * 64 + frow) * 128;
    const int koff0 = (lg ^ f7) * 16;
    const int koff1 = ((4 + lg) ^ f7) * 16;

    // ---- epilogue constants (prologue-loaded; L1-broadcast across frow)
    float bl[16];
    #pragma unroll
    for (int v2 = 0; v2 < 16; ++v2)
        bl[v2] = bperm[(t0 + th) * 64 + (v2 >> 2) * 16 + lg * 4 + (v2 & 3)];
    float pha[8], phd[8];
    #pragma unroll
    for (int i = 0; i < 8; ++i) {
        float2 p2 = *(const float2*)&phig[(size_t)(t0 + th) * NLEAF + lg * 16 + 2 * i];
        pha[i] = p2.x; phd[i] = p2.y - p2.x;
    }

    // ---- K loop: stage -> drain-barrier -> MFMA (single buffer, 2 barriers/step)
    f32x4 acc[4][4] = {};   // [ar (node frag)][bc (row frag)]
    #pragma unroll
    for (int st = 0; st < KSTEPS; ++st) {
        if (st) __syncthreads();           // prev step's frag reads complete
        #pragma unroll
        for (int j = 0; j < 4; ++j) {
            gload16(ag + st * BK + j * 8 * FDIM, &Ash[(wv * 256 + j * 64) * 8]);
            gload16(bg2 + st * BK + j * 8 * FDIM, &Bsh[(wv * 256 + j * 64) * 8]);
        }
        __syncthreads();                    // vmcnt(0) drain: tiles ready
        #pragma unroll
        for (int ks = 0; ks < 2; ++ks) {
            const int ko = ks ? koff1 : koff0;
            bf16x8 af[4], bf_[4];
            #pragma unroll
            for (int ar = 0; ar < 4; ++ar)
                af[ar] = *(const bf16x8*)((const char*)Ash + abase + ar * 2048 + ko);
            #pragma unroll
            for (int bc = 0; bc < 4; ++bc)
                bf_[bc] = *(const bf16x8*)((const char*)Bsh + bbase + bc * 2048 + ko);
            #pragma unroll
            for (int ar = 0; ar < 4; ++ar)
                #pragma unroll
                for (int bc = 0; bc < 4; ++bc)
                    acc[ar][bc] = __builtin_amdgcn_mfma_f32_16x16x32_bf16(af[ar], bf_[bc], acc[ar][bc], 0, 0, 0);
        }
    }

    // ---- in-register epilogue. acc[ar][bc][j] = logit(node slot ar*16+lg*4+j,
    //      batch row bc*16+frow). Lane owns subtree lg (15 nodes) + extra slot.
    float tot[4];
    #pragma unroll
    for (int bc = 0; bc < 4; ++bc) {
        float pv[16];
        #pragma unroll
        for (int v2 = 0; v2 < 16; ++v2) {
            float z = acc[v2 >> 2][bc][v2 & 3] + bl[v2];
            pv[v2] = __builtin_amdgcn_rcpf(1.f + __expf(-z));
        }
        // extra slot: lg0/2 hold root, lg1/3 hold their depth-1 node; exchange.
        float o = __shfl_xor(pv[0], 16);
        float proot = (lg & 1) ? o : pv[0];
        float pd1   = (lg & 1) ? pv[0] : o;
        float mb = ((lg >> 1) ? proot : 1.f - proot) * ((lg & 1) ? pd1 : 1.f - pd1);
        float m3[2], m4[4], m5[8];
        { float t1 = mb * pv[1]; m3[1] = t1; m3[0] = mb - t1; }
        #pragma unroll
        for (int i = 0; i < 2; ++i) { float t1 = m3[i] * pv[2 + i]; m4[2*i+1] = t1; m4[2*i] = m3[i] - t1; }
        #pragma unroll
        for (int i = 0; i < 4; ++i) { float t1 = m4[i] * pv[4 + i]; m5[2*i+1] = t1; m5[2*i] = m4[i] - t1; }
        float s = 0.f;
        #pragma unroll
        for (int i = 0; i < 8; ++i) s += m5[i] * (pha[i] + pv[8 + i] * phd[i]);
        s += __shfl_xor(s, 16);            // sum the 4 subtrees (lg bit0)
        s += __shfl_xor(s, 32);            // (lg bit1)
        tot[bc] = s;
    }
    // lane lg writes bc==lg -> batch row rh*64 + lg*16 + frow = rh*64 + lane
    float vout = (lg & 2) ? ((lg & 1) ? tot[3] : tot[2])
                          : ((lg & 1) ? tot[1] : tot[0]);
    partial[(size_t)(t0 + th) * BATCH + m0 + rh * 64 + lane] = vout;
}

__global__ void reduce_kernel(const float* __restrict__ partial, float* __restrict__ out) {
    int i = blockIdx.x * 256 + threadIdx.x;
    float s = 0.f;
    #pragma unroll
    for (int t = 0; t < NTREE; ++t) s += partial[(size_t)t * BATCH + i];
    out[i] = 0.1f * s;
}

extern "C" void kernel_launch(void* const* d_in, const int* in_sizes, int n_in,
                              void* d_out, int out_size, void* d_ws, size_t ws_size,
                              hipStream_t stream) {
    const float* x   = (const float*)d_in[0];
    const float* W   = (const float*)d_in[1];
    const float* b   = (const float*)d_in[2];
    const float* phi = (const float*)d_in[3];
    float* out = (float*)d_out;

    u16* xb = (u16*)d_ws;                                  // 16384*256 bf16 = 8 MB
    u16* Wb = xb + (size_t)BATCH * FDIM;                   // 32*64*256 bf16 = 1 MB
    float* partial = (float*)(Wb + (size_t)NTREE * NLEAF * FDIM);  // 32*16384 f32 = 2 MB
    float* bperm = partial + (size_t)NTREE * BATCH;        // 32*64 f32 = 8 KB

    convert_kernel<<<2048, 256, 0, stream>>>(x, W, b, xb, Wb, bperm);
    softgbm_main<<<dim3(BATCH / MT, NTREE / TPB), 256, 0, stream>>>(xb, Wb, bperm, phi, partial);
    reduce_kernel<<<BATCH / 256, 256, 0, stream>>>(partial, out);
}